// Round 1
// baseline (782.162 us; speedup 1.0000x reference)
//
#include <hip/hip_runtime.h>

constexpr int DIN = 32;
constexpr int DH  = 64;

// ---------------- scatter: agg[dst] += feat[src], D = 2^LOGD floats/row ----
template<int LOGD>
__global__ __launch_bounds__(256) void scatter_f(
    const float* __restrict__ feat,
    const int*  __restrict__ src,
    const int*  __restrict__ dst,
    float* __restrict__ agg,
    long long total) {
  long long tid = (long long)blockIdx.x * blockDim.x + threadIdx.x;
  if (tid >= total) return;
  long long e = tid >> LOGD;
  int f = (int)(tid & ((1 << LOGD) - 1));
  long long s = src[e];
  long long d = dst[e];
  unsafeAtomicAdd(&agg[(d << LOGD) + f], feat[(s << LOGD) + f]);
}

// scalar scatter for the 1-dim layer-3 aggregation
__global__ __launch_bounds__(256) void scatter_s(
    const float* __restrict__ s_in,
    const int*  __restrict__ src,
    const int*  __restrict__ dst,
    float* __restrict__ sacc,
    int E) {
  int e = blockIdx.x * blockDim.x + threadIdx.x;
  if (e >= E) return;
  unsafeAtomicAdd(&sacc[dst[e]], s_in[src[e]]);
}

// ------------- layer 1: h1 = relu(agg@w1_rel + b1 + x@w1_root) -------------
__global__ __launch_bounds__(256) void layer1_kernel(
    const float* __restrict__ x, const float* __restrict__ agg,
    const float* __restrict__ w_rel, const float* __restrict__ b,
    const float* __restrict__ w_root, float* __restrict__ h1, int n) {
  __shared__ float swr[DH * DIN];   // transposed [j][k]
  __shared__ float swo[DH * DIN];
  __shared__ float sb[DH];
  for (int idx = threadIdx.x; idx < DIN * DH; idx += blockDim.x) {
    int k = idx / DH, j = idx % DH;
    swr[j * DIN + k] = w_rel[idx];
    swo[j * DIN + k] = w_root[idx];
  }
  if (threadIdx.x < DH) sb[threadIdx.x] = b[threadIdx.x];
  __syncthreads();
  int i = blockIdx.x * blockDim.x + threadIdx.x;
  if (i >= n) return;
  float xr[DIN], ar[DIN];
  const float4* xp = (const float4*)(x + (size_t)i * DIN);
  const float4* ap = (const float4*)(agg + (size_t)i * DIN);
#pragma unroll
  for (int q = 0; q < DIN / 4; ++q) {
    float4 v = xp[q];
    xr[q*4+0] = v.x; xr[q*4+1] = v.y; xr[q*4+2] = v.z; xr[q*4+3] = v.w;
    float4 a = ap[q];
    ar[q*4+0] = a.x; ar[q*4+1] = a.y; ar[q*4+2] = a.z; ar[q*4+3] = a.w;
  }
  for (int j = 0; j < DH; ++j) {
    float acc = sb[j];
#pragma unroll
    for (int k = 0; k < DIN; ++k)
      acc = fmaf(ar[k], swr[j*DIN+k], fmaf(xr[k], swo[j*DIN+k], acc));
    h1[(size_t)i * DH + j] = fmaxf(acc, 0.f);
  }
}

// --- layer 2 fused: h2 = relu(agg@w2_rel + b2 + h1@w2_root); s = h2@w3_rel ---
__global__ __launch_bounds__(256) void layer2_kernel(
    const float* __restrict__ h1, const float* __restrict__ agg,
    const float* __restrict__ w_rel, const float* __restrict__ b,
    const float* __restrict__ w_root, const float* __restrict__ w3_rel,
    float* __restrict__ h2, float* __restrict__ s_out, int n) {
  __shared__ float swr[DH * DH];    // transposed [j][k]
  __shared__ float swo[DH * DH];
  __shared__ float sb[DH];
  __shared__ float sw3[DH];
  for (int idx = threadIdx.x; idx < DH * DH; idx += blockDim.x) {
    int k = idx / DH, j = idx % DH;
    swr[j * DH + k] = w_rel[idx];
    swo[j * DH + k] = w_root[idx];
  }
  if (threadIdx.x < DH) {
    sb[threadIdx.x]  = b[threadIdx.x];
    sw3[threadIdx.x] = w3_rel[threadIdx.x];
  }
  __syncthreads();
  int i = blockIdx.x * blockDim.x + threadIdx.x;
  if (i >= n) return;
  float hr[DH], ar[DH];
  const float4* hp = (const float4*)(h1 + (size_t)i * DH);
  const float4* ap = (const float4*)(agg + (size_t)i * DH);
#pragma unroll
  for (int q = 0; q < DH / 4; ++q) {
    float4 v = hp[q];
    hr[q*4+0] = v.x; hr[q*4+1] = v.y; hr[q*4+2] = v.z; hr[q*4+3] = v.w;
    float4 a = ap[q];
    ar[q*4+0] = a.x; ar[q*4+1] = a.y; ar[q*4+2] = a.z; ar[q*4+3] = a.w;
  }
  float sdot = 0.f;
  for (int j = 0; j < DH; ++j) {
    float acc = sb[j];
#pragma unroll
    for (int k = 0; k < DH; ++k)
      acc = fmaf(ar[k], swr[j*DH+k], fmaf(hr[k], swo[j*DH+k], acc));
    float r = fmaxf(acc, 0.f);
    h2[(size_t)i * DH + j] = r;
    sdot = fmaf(r, sw3[j], sdot);
  }
  s_out[i] = sdot;
}

// ------------- final: out = sacc + b3 + h2@w3_root -------------------------
__global__ __launch_bounds__(256) void final_kernel(
    const float* __restrict__ h2, const float* __restrict__ sacc,
    const float* __restrict__ w3_root, const float* __restrict__ b3,
    float* __restrict__ out, int n) {
  __shared__ float sw[DH];
  if (threadIdx.x < DH) sw[threadIdx.x] = w3_root[threadIdx.x];
  __syncthreads();
  int i = blockIdx.x * blockDim.x + threadIdx.x;
  if (i >= n) return;
  float acc = sacc[i] + b3[0];
  const float4* hp = (const float4*)(h2 + (size_t)i * DH);
#pragma unroll
  for (int q = 0; q < DH / 4; ++q) {
    float4 v = hp[q];
    acc = fmaf(v.x, sw[q*4+0], acc);
    acc = fmaf(v.y, sw[q*4+1], acc);
    acc = fmaf(v.z, sw[q*4+2], acc);
    acc = fmaf(v.w, sw[q*4+3], acc);
  }
  out[i] = acc;
}

extern "C" void kernel_launch(void* const* d_in, const int* in_sizes, int n_in,
                              void* d_out, int out_size, void* d_ws, size_t ws_size,
                              hipStream_t stream) {
  const float* x       = (const float*)d_in[0];
  const float* w1_rel  = (const float*)d_in[1];
  const float* b1      = (const float*)d_in[2];
  const float* w1_root = (const float*)d_in[3];
  const float* w2_rel  = (const float*)d_in[4];
  const float* b2      = (const float*)d_in[5];
  const float* w2_root = (const float*)d_in[6];
  const float* w3_rel  = (const float*)d_in[7];
  const float* b3      = (const float*)d_in[8];
  const float* w3_root = (const float*)d_in[9];
  const int*   edge    = (const int*)d_in[10];

  const int n = in_sizes[0] / DIN;        // 100000
  const int E = in_sizes[10] / 2;         // 1600000
  const int* src = edge;
  const int* dst = edge + E;

  float* AGG  = (float*)d_ws;             // n*DH
  float* H1   = AGG + (size_t)n * DH;     // n*DH
  float* H2   = H1  + (size_t)n * DH;     // n*DH
  float* S    = H2  + (size_t)n * DH;     // n
  float* SACC = S + n;                    // n

  const int B = 256;
  const int gn = (n + B - 1) / B;

  // ---- layer 1 ----
  hipMemsetAsync(AGG, 0, (size_t)n * DIN * sizeof(float), stream);
  {
    long long tot = (long long)E * DIN;
    unsigned int g = (unsigned int)((tot + B - 1) / B);
    scatter_f<5><<<g, B, 0, stream>>>(x, src, dst, AGG, tot);
  }
  layer1_kernel<<<gn, B, 0, stream>>>(x, AGG, w1_rel, b1, w1_root, H1, n);

  // ---- layer 2 ----
  hipMemsetAsync(AGG, 0, (size_t)n * DH * sizeof(float), stream);
  {
    long long tot = (long long)E * DH;
    unsigned int g = (unsigned int)((tot + B - 1) / B);
    scatter_f<6><<<g, B, 0, stream>>>(H1, src, dst, AGG, tot);
  }
  layer2_kernel<<<gn, B, 0, stream>>>(H1, AGG, w2_rel, b2, w2_root, w3_rel, H2, S, n);

  // ---- layer 3 (pre-transformed by w3_rel, scatter scalars) ----
  hipMemsetAsync(SACC, 0, (size_t)n * sizeof(float), stream);
  scatter_s<<<(E + B - 1) / B, B, 0, stream>>>(S, src, dst, SACC, E);
  final_kernel<<<gn, B, 0, stream>>>(H2, SACC, w3_root, b3, (float*)d_out, n);
}

// Round 2
// 521.986 us; speedup vs baseline: 1.4984x; 1.4984x over previous
//
#include <hip/hip_runtime.h>

constexpr int DIN = 32;
constexpr int DH  = 64;

// ===================== CSR build =====================

__global__ __launch_bounds__(256) void k_hist(
    const int* __restrict__ dst, int* __restrict__ deg, int E) {
  int e = blockIdx.x * 256 + threadIdx.x;
  if (e >= E) return;
  atomicAdd(&deg[dst[e]], 1);
}

// block scans 1024 elements (256 threads x 4)
__global__ __launch_bounds__(256) void k_scan1(
    const int* __restrict__ deg, int* __restrict__ ex,
    int* __restrict__ bsum, int n) {
  __shared__ int ts[256];
  int base = blockIdx.x * 1024 + threadIdx.x * 4;
  int v[4];
  int s = 0;
#pragma unroll
  for (int q = 0; q < 4; ++q) {
    int idx = base + q;
    v[q] = (idx < n) ? deg[idx] : 0;
    s += v[q];
  }
  ts[threadIdx.x] = s;
  __syncthreads();
  for (int off = 1; off < 256; off <<= 1) {
    int val = (threadIdx.x >= off) ? ts[threadIdx.x - off] : 0;
    __syncthreads();
    ts[threadIdx.x] += val;
    __syncthreads();
  }
  int run = ts[threadIdx.x] - s;  // exclusive prefix of this thread
#pragma unroll
  for (int q = 0; q < 4; ++q) {
    int idx = base + q;
    if (idx < n) ex[idx] = run;
    run += v[q];
  }
  if (threadIdx.x == 255) bsum[blockIdx.x] = ts[255];
}

__global__ __launch_bounds__(256) void k_scan2(int* __restrict__ bsum, int nb) {
  __shared__ int ts[256];
  int v = (threadIdx.x < nb) ? bsum[threadIdx.x] : 0;
  ts[threadIdx.x] = v;
  __syncthreads();
  for (int off = 1; off < 256; off <<= 1) {
    int val = (threadIdx.x >= off) ? ts[threadIdx.x - off] : 0;
    __syncthreads();
    ts[threadIdx.x] += val;
    __syncthreads();
  }
  if (threadIdx.x < nb) bsum[threadIdx.x] = ts[threadIdx.x] - v;  // exclusive
}

__global__ __launch_bounds__(256) void k_scan3(
    int* __restrict__ rp, const int* __restrict__ bsum,
    int* __restrict__ cur, int n, int E) {
  int i = blockIdx.x * 256 + threadIdx.x;
  if (i > n) return;
  if (i == n) { rp[n] = E; return; }
  int val = rp[i] + bsum[i >> 10];
  rp[i] = val;
  cur[i] = val;
}

__global__ __launch_bounds__(256) void k_fill(
    const int* __restrict__ src, const int* __restrict__ dst,
    int* __restrict__ cur, int* __restrict__ ssrc, int E) {
  int e = blockIdx.x * 256 + threadIdx.x;
  if (e >= E) return;
  int pos = atomicAdd(&cur[dst[e]], 1);
  ssrc[pos] = src[e];
}

// ===================== gather-based segment sums =====================

// one lane per (node, feature); D = 1<<LOGD features
template<int LOGD>
__global__ __launch_bounds__(256) void k_gather(
    const float* __restrict__ feat, const int* __restrict__ rp,
    const int* __restrict__ ssrc, float* __restrict__ agg, int n) {
  int t = blockIdx.x * 256 + threadIdx.x;
  int node = t >> LOGD;
  int f = t & ((1 << LOGD) - 1);
  if (node >= n) return;
  int beg = rp[node], end = rp[node + 1];
  float acc = 0.f;
  int e = beg;
  for (; e + 1 < end; e += 2) {
    int s0 = ssrc[e];
    int s1 = ssrc[e + 1];
    float v0 = feat[((size_t)s0 << LOGD) + f];
    float v1 = feat[((size_t)s1 << LOGD) + f];
    acc += v0;
    acc += v1;
  }
  if (e < end) acc += feat[((size_t)ssrc[e] << LOGD) + f];
  agg[((size_t)node << LOGD) + f] = acc;
}

// scalar segment sum for layer 3 (thread per node)
__global__ __launch_bounds__(256) void k_gather_s(
    const float* __restrict__ sv, const int* __restrict__ rp,
    const int* __restrict__ ssrc, float* __restrict__ sacc, int n) {
  int i = blockIdx.x * 256 + threadIdx.x;
  if (i >= n) return;
  int beg = rp[i], end = rp[i + 1];
  float a = 0.f;
  for (int e = beg; e < end; ++e) a += sv[ssrc[e]];
  sacc[i] = a;
}

// ===================== dense layers =====================

__global__ __launch_bounds__(256) void layer1_kernel(
    const float* __restrict__ x, const float* __restrict__ agg,
    const float* __restrict__ w_rel, const float* __restrict__ b,
    const float* __restrict__ w_root, float* __restrict__ h1, int n) {
  __shared__ float swr[DH * DIN];   // transposed [j][k]
  __shared__ float swo[DH * DIN];
  __shared__ float sb[DH];
  for (int idx = threadIdx.x; idx < DIN * DH; idx += blockDim.x) {
    int k = idx / DH, j = idx % DH;
    swr[j * DIN + k] = w_rel[idx];
    swo[j * DIN + k] = w_root[idx];
  }
  if (threadIdx.x < DH) sb[threadIdx.x] = b[threadIdx.x];
  __syncthreads();
  int i = blockIdx.x * blockDim.x + threadIdx.x;
  if (i >= n) return;
  float xr[DIN], ar[DIN];
  const float4* xp = (const float4*)(x + (size_t)i * DIN);
  const float4* ap = (const float4*)(agg + (size_t)i * DIN);
#pragma unroll
  for (int q = 0; q < DIN / 4; ++q) {
    float4 v = xp[q];
    xr[q*4+0] = v.x; xr[q*4+1] = v.y; xr[q*4+2] = v.z; xr[q*4+3] = v.w;
    float4 a = ap[q];
    ar[q*4+0] = a.x; ar[q*4+1] = a.y; ar[q*4+2] = a.z; ar[q*4+3] = a.w;
  }
  for (int j = 0; j < DH; ++j) {
    float acc = sb[j];
#pragma unroll
    for (int k = 0; k < DIN; ++k)
      acc = fmaf(ar[k], swr[j*DIN+k], fmaf(xr[k], swo[j*DIN+k], acc));
    h1[(size_t)i * DH + j] = fmaxf(acc, 0.f);
  }
}

__global__ __launch_bounds__(256) void layer2_kernel(
    const float* __restrict__ h1, const float* __restrict__ agg,
    const float* __restrict__ w_rel, const float* __restrict__ b,
    const float* __restrict__ w_root, const float* __restrict__ w3_rel,
    float* __restrict__ h2, float* __restrict__ s_out, int n) {
  __shared__ float swr[DH * DH];    // transposed [j][k]
  __shared__ float swo[DH * DH];
  __shared__ float sb[DH];
  __shared__ float sw3[DH];
  for (int idx = threadIdx.x; idx < DH * DH; idx += blockDim.x) {
    int k = idx / DH, j = idx % DH;
    swr[j * DH + k] = w_rel[idx];
    swo[j * DH + k] = w_root[idx];
  }
  if (threadIdx.x < DH) {
    sb[threadIdx.x]  = b[threadIdx.x];
    sw3[threadIdx.x] = w3_rel[threadIdx.x];
  }
  __syncthreads();
  int i = blockIdx.x * blockDim.x + threadIdx.x;
  if (i >= n) return;
  float hr[DH], ar[DH];
  const float4* hp = (const float4*)(h1 + (size_t)i * DH);
  const float4* ap = (const float4*)(agg + (size_t)i * DH);
#pragma unroll
  for (int q = 0; q < DH / 4; ++q) {
    float4 v = hp[q];
    hr[q*4+0] = v.x; hr[q*4+1] = v.y; hr[q*4+2] = v.z; hr[q*4+3] = v.w;
    float4 a = ap[q];
    ar[q*4+0] = a.x; ar[q*4+1] = a.y; ar[q*4+2] = a.z; ar[q*4+3] = a.w;
  }
  float sdot = 0.f;
  for (int j = 0; j < DH; ++j) {
    float acc = sb[j];
#pragma unroll
    for (int k = 0; k < DH; ++k)
      acc = fmaf(ar[k], swr[j*DH+k], fmaf(hr[k], swo[j*DH+k], acc));
    float r = fmaxf(acc, 0.f);
    h2[(size_t)i * DH + j] = r;
    sdot = fmaf(r, sw3[j], sdot);
  }
  s_out[i] = sdot;
}

__global__ __launch_bounds__(256) void final_kernel(
    const float* __restrict__ h2, const float* __restrict__ sacc,
    const float* __restrict__ w3_root, const float* __restrict__ b3,
    float* __restrict__ out, int n) {
  __shared__ float sw[DH];
  if (threadIdx.x < DH) sw[threadIdx.x] = w3_root[threadIdx.x];
  __syncthreads();
  int i = blockIdx.x * blockDim.x + threadIdx.x;
  if (i >= n) return;
  float acc = sacc[i] + b3[0];
  const float4* hp = (const float4*)(h2 + (size_t)i * DH);
#pragma unroll
  for (int q = 0; q < DH / 4; ++q) {
    float4 v = hp[q];
    acc = fmaf(v.x, sw[q*4+0], acc);
    acc = fmaf(v.y, sw[q*4+1], acc);
    acc = fmaf(v.z, sw[q*4+2], acc);
    acc = fmaf(v.w, sw[q*4+3], acc);
  }
  out[i] = acc;
}

// ===================== launch =====================

extern "C" void kernel_launch(void* const* d_in, const int* in_sizes, int n_in,
                              void* d_out, int out_size, void* d_ws, size_t ws_size,
                              hipStream_t stream) {
  const float* x       = (const float*)d_in[0];
  const float* w1_rel  = (const float*)d_in[1];
  const float* b1      = (const float*)d_in[2];
  const float* w1_root = (const float*)d_in[3];
  const float* w2_rel  = (const float*)d_in[4];
  const float* b2      = (const float*)d_in[5];
  const float* w2_root = (const float*)d_in[6];
  const float* w3_rel  = (const float*)d_in[7];
  const float* b3      = (const float*)d_in[8];
  const float* w3_root = (const float*)d_in[9];
  const int*   edge    = (const int*)d_in[10];

  const int n = in_sizes[0] / DIN;        // 100000
  const int E = in_sizes[10] / 2;         // 1600000
  const int* src = edge;
  const int* dst = edge + E;

  const size_t n64 = (size_t)n * DH;
  float* AGG  = (float*)d_ws;             // n*64 (also used as n*32 for layer 1)
  float* H1   = AGG + n64;
  float* H2   = H1 + n64;
  float* S    = H2 + n64;
  float* SACC = S + n;
  int* RP     = (int*)(SACC + n);         // n+1
  int* CUR    = RP + (n + 1);             // n  (deg, then cursor)
  int* SSRC   = CUR + n;                  // E
  int* BSUM   = SSRC + E;                 // <=256

  const int B = 256;
  const int gn  = (n + B - 1) / B;
  const int gE  = (E + B - 1) / B;
  const int nb  = (n + 1023) / 1024;      // scan blocks (<=256 required)

  // ---- CSR build (counting sort by dst) ----
  hipMemsetAsync(CUR, 0, (size_t)n * sizeof(int), stream);
  k_hist<<<gE, B, 0, stream>>>(dst, CUR, E);
  k_scan1<<<nb, B, 0, stream>>>(CUR, RP, BSUM, n);
  k_scan2<<<1, B, 0, stream>>>(BSUM, nb);
  k_scan3<<<(n + 1 + B - 1) / B, B, 0, stream>>>(RP, BSUM, CUR, n, E);
  k_fill<<<gE, B, 0, stream>>>(src, dst, CUR, SSRC, E);

  // ---- layer 1 ----
  {
    long long tot = (long long)n * DIN;
    k_gather<5><<<(unsigned)((tot + B - 1) / B), B, 0, stream>>>(x, RP, SSRC, AGG, n);
  }
  layer1_kernel<<<gn, B, 0, stream>>>(x, AGG, w1_rel, b1, w1_root, H1, n);

  // ---- layer 2 ----
  {
    long long tot = (long long)n * DH;
    k_gather<6><<<(unsigned)((tot + B - 1) / B), B, 0, stream>>>(H1, RP, SSRC, AGG, n);
  }
  layer2_kernel<<<gn, B, 0, stream>>>(H1, AGG, w2_rel, b2, w2_root, w3_rel, H2, S, n);

  // ---- layer 3 (pre-projected by w3_rel in layer2_kernel) ----
  k_gather_s<<<gn, B, 0, stream>>>(S, RP, SSRC, SACC, n);
  final_kernel<<<gn, B, 0, stream>>>(H2, SACC, w3_root, b3, (float*)d_out, n);
}

// Round 3
// 433.664 us; speedup vs baseline: 1.8036x; 1.2037x over previous
//
#include <hip/hip_runtime.h>
#include <hip/hip_fp16.h>

constexpr int DIN = 32;
constexpr int DH  = 64;

// ===================== CSR build =====================

__global__ __launch_bounds__(256) void k_hist(
    const int* __restrict__ dst, int* __restrict__ deg, int E) {
  int e = blockIdx.x * 256 + threadIdx.x;
  if (e >= E) return;
  atomicAdd(&deg[dst[e]], 1);
}

__global__ __launch_bounds__(256) void k_scan1(
    const int* __restrict__ deg, int* __restrict__ ex,
    int* __restrict__ bsum, int n) {
  __shared__ int ts[256];
  int base = blockIdx.x * 1024 + threadIdx.x * 4;
  int v[4];
  int s = 0;
#pragma unroll
  for (int q = 0; q < 4; ++q) {
    int idx = base + q;
    v[q] = (idx < n) ? deg[idx] : 0;
    s += v[q];
  }
  ts[threadIdx.x] = s;
  __syncthreads();
  for (int off = 1; off < 256; off <<= 1) {
    int val = (threadIdx.x >= off) ? ts[threadIdx.x - off] : 0;
    __syncthreads();
    ts[threadIdx.x] += val;
    __syncthreads();
  }
  int run = ts[threadIdx.x] - s;
#pragma unroll
  for (int q = 0; q < 4; ++q) {
    int idx = base + q;
    if (idx < n) ex[idx] = run;
    run += v[q];
  }
  if (threadIdx.x == 255) bsum[blockIdx.x] = ts[255];
}

__global__ __launch_bounds__(256) void k_scan2(int* __restrict__ bsum, int nb) {
  __shared__ int ts[256];
  int v = (threadIdx.x < nb) ? bsum[threadIdx.x] : 0;
  ts[threadIdx.x] = v;
  __syncthreads();
  for (int off = 1; off < 256; off <<= 1) {
    int val = (threadIdx.x >= off) ? ts[threadIdx.x - off] : 0;
    __syncthreads();
    ts[threadIdx.x] += val;
    __syncthreads();
  }
  if (threadIdx.x < nb) bsum[threadIdx.x] = ts[threadIdx.x] - v;
}

__global__ __launch_bounds__(256) void k_scan3(
    int* __restrict__ rp, const int* __restrict__ bsum,
    int* __restrict__ cur, int n, int E) {
  int i = blockIdx.x * 256 + threadIdx.x;
  if (i > n) return;
  if (i == n) { rp[n] = E; return; }
  int val = rp[i] + bsum[i >> 10];
  rp[i] = val;
  cur[i] = val;
}

__global__ __launch_bounds__(256) void k_fill(
    const int* __restrict__ src, const int* __restrict__ dst,
    int* __restrict__ cur, int* __restrict__ ssrc, int E) {
  int e = blockIdx.x * 256 + threadIdx.x;
  if (e >= E) return;
  int pos = atomicAdd(&cur[dst[e]], 1);
  ssrc[pos] = src[e];
}

// ===================== fp32 -> fp16 conversion =====================

__global__ __launch_bounds__(256) void k_tohalf(
    const float2* __restrict__ in, __half2* __restrict__ out, int n2) {
  int i = blockIdx.x * 256 + threadIdx.x;
  if (i >= n2) return;
  float2 v = in[i];
  out[i] = __floats2half2_rn(v.x, v.y);
}

// ===================== gather-based segment sums (fp16 features) ============

// g = 1<<LOGG lanes per node, each lane covers 2 features (half2). D = 2*g.
template<int LOGG>
__global__ __launch_bounds__(256) void k_gather_h(
    const __half2* __restrict__ feat, const int* __restrict__ rp,
    const int* __restrict__ ssrc, float2* __restrict__ agg, int n) {
  int t = blockIdx.x * 256 + threadIdx.x;
  int node = t >> LOGG;
  int f2 = t & ((1 << LOGG) - 1);
  if (node >= n) return;
  int beg = rp[node], end = rp[node + 1];
  float ax = 0.f, ay = 0.f;
  int e = beg;
  for (; e + 1 < end; e += 2) {
    int s0 = ssrc[e];
    int s1 = ssrc[e + 1];
    float2 v0 = __half22float2(feat[((size_t)s0 << LOGG) + f2]);
    float2 v1 = __half22float2(feat[((size_t)s1 << LOGG) + f2]);
    ax += v0.x; ay += v0.y;
    ax += v1.x; ay += v1.y;
  }
  if (e < end) {
    float2 v = __half22float2(feat[((size_t)ssrc[e] << LOGG) + f2]);
    ax += v.x; ay += v.y;
  }
  agg[((size_t)node << LOGG) + f2] = make_float2(ax, ay);
}

// scalar segment sum for layer 3 (thread per node)
__global__ __launch_bounds__(256) void k_gather_s(
    const float* __restrict__ sv, const int* __restrict__ rp,
    const int* __restrict__ ssrc, float* __restrict__ sacc, int n) {
  int i = blockIdx.x * 256 + threadIdx.x;
  if (i >= n) return;
  int beg = rp[i], end = rp[i + 1];
  float a = 0.f;
  for (int e = beg; e < end; ++e) a += sv[ssrc[e]];
  sacc[i] = a;
}

// ===================== dense layers =====================

union U16 { uint4 u; __half2 h[4]; };

// h1 = relu(agg@w1_rel + b1 + x@w1_root), emitted as fp16
__global__ __launch_bounds__(256) void layer1_kernel(
    const float* __restrict__ x, const float* __restrict__ agg,
    const float* __restrict__ w_rel, const float* __restrict__ b,
    const float* __restrict__ w_root, __half2* __restrict__ h1h, int n) {
  __shared__ float swr[DH * DIN];   // [j][k], written linearly (no bank conflicts)
  __shared__ float swo[DH * DIN];
  __shared__ float sb[DH];
  for (int idx = threadIdx.x; idx < DIN * DH; idx += blockDim.x) {
    int j = idx / DIN, k = idx % DIN;
    swr[idx] = w_rel[k * DH + j];   // strided global read, L1/L2-cached (4 KB)
    swo[idx] = w_root[k * DH + j];
  }
  if (threadIdx.x < DH) sb[threadIdx.x] = b[threadIdx.x];
  __syncthreads();
  int i = blockIdx.x * blockDim.x + threadIdx.x;
  if (i >= n) return;
  float xr[DIN], ar[DIN];
  const float4* xp = (const float4*)(x + (size_t)i * DIN);
  const float4* ap = (const float4*)(agg + (size_t)i * DIN);
#pragma unroll
  for (int q = 0; q < DIN / 4; ++q) {
    float4 v = xp[q];
    xr[q*4+0] = v.x; xr[q*4+1] = v.y; xr[q*4+2] = v.z; xr[q*4+3] = v.w;
    float4 a = ap[q];
    ar[q*4+0] = a.x; ar[q*4+1] = a.y; ar[q*4+2] = a.z; ar[q*4+3] = a.w;
  }
  for (int j = 0; j < DH; j += 2) {
    float acc0 = sb[j], acc1 = sb[j + 1];
#pragma unroll
    for (int k = 0; k < DIN; ++k) {
      acc0 = fmaf(ar[k], swr[j*DIN+k],     fmaf(xr[k], swo[j*DIN+k],     acc0));
      acc1 = fmaf(ar[k], swr[(j+1)*DIN+k], fmaf(xr[k], swo[(j+1)*DIN+k], acc1));
    }
    h1h[(size_t)i * (DH/2) + (j >> 1)] =
        __floats2half2_rn(fmaxf(acc0, 0.f), fmaxf(acc1, 0.f));
  }
}

// h2 = relu(agg@w2_rel + b2 + h1@w2_root); s = h2@w3_rel  (h1 is fp16)
__global__ __launch_bounds__(256) void layer2_kernel(
    const __half2* __restrict__ h1h, const float* __restrict__ agg,
    const float* __restrict__ w_rel, const float* __restrict__ b,
    const float* __restrict__ w_root, const float* __restrict__ w3_rel,
    float* __restrict__ h2, float* __restrict__ s_out, int n) {
  __shared__ float swr[DH * DH];    // [j][k], linear writes
  __shared__ float swo[DH * DH];
  __shared__ float sb[DH];
  __shared__ float sw3[DH];
  for (int idx = threadIdx.x; idx < DH * DH; idx += blockDim.x) {
    int j = idx / DH, k = idx % DH;
    swr[idx] = w_rel[k * DH + j];
    swo[idx] = w_root[k * DH + j];
  }
  if (threadIdx.x < DH) {
    sb[threadIdx.x]  = b[threadIdx.x];
    sw3[threadIdx.x] = w3_rel[threadIdx.x];
  }
  __syncthreads();
  int i = blockIdx.x * blockDim.x + threadIdx.x;
  if (i >= n) return;
  float hr[DH], ar[DH];
  const uint4* hp = (const uint4*)(h1h + (size_t)i * (DH/2));
#pragma unroll
  for (int q = 0; q < DH / 8; ++q) {      // 8 x 16B loads = 64 halfs
    U16 u; u.u = hp[q];
#pragma unroll
    for (int c = 0; c < 4; ++c) {
      float2 v = __half22float2(u.h[c]);
      hr[q*8 + 2*c]     = v.x;
      hr[q*8 + 2*c + 1] = v.y;
    }
  }
  const float4* ap = (const float4*)(agg + (size_t)i * DH);
#pragma unroll
  for (int q = 0; q < DH / 4; ++q) {
    float4 a = ap[q];
    ar[q*4+0] = a.x; ar[q*4+1] = a.y; ar[q*4+2] = a.z; ar[q*4+3] = a.w;
  }
  float sdot = 0.f;
  for (int j = 0; j < DH; ++j) {
    float acc = sb[j];
#pragma unroll
    for (int k = 0; k < DH; ++k)
      acc = fmaf(ar[k], swr[j*DH+k], fmaf(hr[k], swo[j*DH+k], acc));
    float r = fmaxf(acc, 0.f);
    h2[(size_t)i * DH + j] = r;
    sdot = fmaf(r, sw3[j], sdot);
  }
  s_out[i] = sdot;
}

__global__ __launch_bounds__(256) void final_kernel(
    const float* __restrict__ h2, const float* __restrict__ sacc,
    const float* __restrict__ w3_root, const float* __restrict__ b3,
    float* __restrict__ out, int n) {
  __shared__ float sw[DH];
  if (threadIdx.x < DH) sw[threadIdx.x] = w3_root[threadIdx.x];
  __syncthreads();
  int i = blockIdx.x * blockDim.x + threadIdx.x;
  if (i >= n) return;
  float acc = sacc[i] + b3[0];
  const float4* hp = (const float4*)(h2 + (size_t)i * DH);
#pragma unroll
  for (int q = 0; q < DH / 4; ++q) {
    float4 v = hp[q];
    acc = fmaf(v.x, sw[q*4+0], acc);
    acc = fmaf(v.y, sw[q*4+1], acc);
    acc = fmaf(v.z, sw[q*4+2], acc);
    acc = fmaf(v.w, sw[q*4+3], acc);
  }
  out[i] = acc;
}

// ===================== launch =====================

extern "C" void kernel_launch(void* const* d_in, const int* in_sizes, int n_in,
                              void* d_out, int out_size, void* d_ws, size_t ws_size,
                              hipStream_t stream) {
  const float* x       = (const float*)d_in[0];
  const float* w1_rel  = (const float*)d_in[1];
  const float* b1      = (const float*)d_in[2];
  const float* w1_root = (const float*)d_in[3];
  const float* w2_rel  = (const float*)d_in[4];
  const float* b2      = (const float*)d_in[5];
  const float* w2_root = (const float*)d_in[6];
  const float* w3_rel  = (const float*)d_in[7];
  const float* b3      = (const float*)d_in[8];
  const float* w3_root = (const float*)d_in[9];
  const int*   edge    = (const int*)d_in[10];

  const int n = in_sizes[0] / DIN;        // 100000
  const int E = in_sizes[10] / 2;         // 1600000
  const int* src = edge;
  const int* dst = edge + E;

  const size_t n64 = (size_t)n * DH;
  float*   AGG  = (float*)d_ws;                 // n*64 f32 (layer1 uses n*32)
  float*   H2   = AGG + n64;                    // n*64 f32
  __half2* H1h  = (__half2*)(H2 + n64);         // n*32 half2 (= n*64 half)
  __half2* XH   = H1h + (size_t)n * (DH/2);     // n*16 half2 (= n*32 half)
  float*   S    = (float*)(XH + (size_t)n * (DIN/2)); // n
  float*   SACC = S + n;                        // n
  int* RP   = (int*)(SACC + n);                 // n+1
  int* CUR  = RP + (n + 1);                     // n
  int* SSRC = CUR + n;                          // E
  int* BSUM = SSRC + E;                         // <=256

  const int B = 256;
  const int gn = (n + B - 1) / B;
  const int gE = (E + B - 1) / B;
  const int nb = (n + 1023) / 1024;

  // ---- CSR build (counting sort by dst) ----
  hipMemsetAsync(CUR, 0, (size_t)n * sizeof(int), stream);
  k_hist<<<gE, B, 0, stream>>>(dst, CUR, E);
  k_scan1<<<nb, B, 0, stream>>>(CUR, RP, BSUM, n);
  k_scan2<<<1, B, 0, stream>>>(BSUM, nb);
  k_scan3<<<(n + 1 + B - 1) / B, B, 0, stream>>>(RP, BSUM, CUR, n, E);
  k_fill<<<gE, B, 0, stream>>>(src, dst, CUR, SSRC, E);

  // ---- x -> fp16 ----
  {
    int n2 = n * (DIN / 2);
    k_tohalf<<<(n2 + B - 1) / B, B, 0, stream>>>((const float2*)x, XH, n2);
  }

  // ---- layer 1 ----  (16 lanes/node, 32 features)
  {
    long long tot = (long long)n * (DIN / 2);
    k_gather_h<4><<<(unsigned)((tot + B - 1) / B), B, 0, stream>>>(
        XH, RP, SSRC, (float2*)AGG, n);
  }
  layer1_kernel<<<gn, B, 0, stream>>>(x, AGG, w1_rel, b1, w1_root, H1h, n);

  // ---- layer 2 ----  (32 lanes/node, 64 features)
  {
    long long tot = (long long)n * (DH / 2);
    k_gather_h<5><<<(unsigned)((tot + B - 1) / B), B, 0, stream>>>(
        H1h, RP, SSRC, (float2*)AGG, n);
  }
  layer2_kernel<<<gn, B, 0, stream>>>(H1h, AGG, w2_rel, b2, w2_root, w3_rel, H2, S, n);

  // ---- layer 3 (pre-projected by w3_rel in layer2_kernel) ----
  k_gather_s<<<gn, B, 0, stream>>>(S, RP, SSRC, SACC, n);
  final_kernel<<<gn, B, 0, stream>>>(H2, SACC, w3_root, b3, (float*)d_out, n);
}

// Round 4
// 330.621 us; speedup vs baseline: 2.3657x; 1.3117x over previous
//
#include <hip/hip_runtime.h>
#include <hip/hip_fp16.h>

constexpr int DIN = 32;
constexpr int DH  = 64;
constexpr int NBSHIFT = 8;            // 256 nodes per coarse bucket
constexpr int TILE_A  = 16384;        // edges per phase-A block

// ===================== CSR build =====================

__global__ __launch_bounds__(256) void k_hist(
    const int* __restrict__ dst, int* __restrict__ deg, int E) {
  int e = blockIdx.x * 256 + threadIdx.x;
  if (e >= E) return;
  atomicAdd(&deg[dst[e]], 1);
}

__global__ __launch_bounds__(256) void k_scan1(
    const int* __restrict__ deg, int* __restrict__ ex,
    int* __restrict__ bsum, int n) {
  __shared__ int ts[256];
  int base = blockIdx.x * 1024 + threadIdx.x * 4;
  int v[4];
  int s = 0;
#pragma unroll
  for (int q = 0; q < 4; ++q) {
    int idx = base + q;
    v[q] = (idx < n) ? deg[idx] : 0;
    s += v[q];
  }
  ts[threadIdx.x] = s;
  __syncthreads();
  for (int off = 1; off < 256; off <<= 1) {
    int val = (threadIdx.x >= off) ? ts[threadIdx.x - off] : 0;
    __syncthreads();
    ts[threadIdx.x] += val;
    __syncthreads();
  }
  int run = ts[threadIdx.x] - s;
#pragma unroll
  for (int q = 0; q < 4; ++q) {
    int idx = base + q;
    if (idx < n) ex[idx] = run;
    run += v[q];
  }
  if (threadIdx.x == 255) bsum[blockIdx.x] = ts[255];
}

__global__ __launch_bounds__(256) void k_scan2(int* __restrict__ bsum, int nb) {
  __shared__ int ts[256];
  int v = (threadIdx.x < nb) ? bsum[threadIdx.x] : 0;
  ts[threadIdx.x] = v;
  __syncthreads();
  for (int off = 1; off < 256; off <<= 1) {
    int val = (threadIdx.x >= off) ? ts[threadIdx.x - off] : 0;
    __syncthreads();
    ts[threadIdx.x] += val;
    __syncthreads();
  }
  if (threadIdx.x < nb) bsum[threadIdx.x] = ts[threadIdx.x] - v;
}

// finalize rp; also initialize coarse-bucket cursors bcur[b] = rp[b*256]
__global__ __launch_bounds__(256) void k_scan3(
    int* __restrict__ rp, const int* __restrict__ bsum,
    int* __restrict__ bcur, int n, int E) {
  int i = blockIdx.x * 256 + threadIdx.x;
  if (i > n) return;
  if (i == n) { rp[n] = E; return; }
  int val = rp[i] + bsum[i >> 10];
  rp[i] = val;
  if ((i & 255) == 0) bcur[i >> NBSHIFT] = val;
}

// Phase A: bin edges into coarse dst-buckets, packed as (dst&255)<<17 | src.
// Requires n < 2^17 (n = 100000 here).
__global__ __launch_bounds__(256) void k_binA(
    const int* __restrict__ src, const int* __restrict__ dst,
    int* __restrict__ bcur, unsigned* __restrict__ bin,
    int E, int nbuckets) {
  __shared__ int hist[512];
  __shared__ int base[512];
  long long t0 = (long long)blockIdx.x * TILE_A;
  int cnt = (int)min((long long)TILE_A, (long long)E - t0);
  for (int i = threadIdx.x; i < nbuckets; i += 256) hist[i] = 0;
  __syncthreads();
  for (int r = threadIdx.x; r < cnt; r += 256)
    atomicAdd(&hist[dst[t0 + r] >> NBSHIFT], 1);
  __syncthreads();
  for (int i = threadIdx.x; i < nbuckets; i += 256) {
    int c = hist[i];
    base[i] = c ? atomicAdd(&bcur[i], c) : 0;
    hist[i] = 0;                       // reuse as local cursor
  }
  __syncthreads();
  for (int r = threadIdx.x; r < cnt; r += 256) {
    int d = dst[t0 + r];
    int s = src[t0 + r];
    int b = d >> NBSHIFT;
    int off = atomicAdd(&hist[b], 1);
    bin[base[b] + off] = ((unsigned)(d & 255) << 17) | (unsigned)s;
  }
}

// Phase B: exact counting sort inside each bucket; ssrc writes stay in a
// ~16 KB contiguous region per block -> full line coverage before eviction.
__global__ __launch_bounds__(256) void k_fillB(
    const unsigned* __restrict__ bin, const int* __restrict__ rp,
    int* __restrict__ ssrc, int n) {
  __shared__ int cur[256];
  int nbase = blockIdx.x << NBSHIFT;
  int nend = min(nbase + 256, n);
  int nn = nend - nbase;
  if (threadIdx.x < nn) cur[threadIdx.x] = rp[nbase + threadIdx.x];
  __syncthreads();
  int ebeg = rp[nbase];
  int eend = rp[nend];
  for (int e = ebeg + (int)threadIdx.x; e < eend; e += 256) {
    unsigned u = bin[e];
    int dlow = (int)(u >> 17);
    int s = (int)(u & 0x1FFFF);
    int pos = atomicAdd(&cur[dlow], 1);
    ssrc[pos] = s;
  }
}

// ===================== fp32 -> fp16 conversion =====================

__global__ __launch_bounds__(256) void k_tohalf(
    const float2* __restrict__ in, __half2* __restrict__ out, int n2) {
  int i = blockIdx.x * 256 + threadIdx.x;
  if (i >= n2) return;
  float2 v = in[i];
  out[i] = __floats2half2_rn(v.x, v.y);
}

// ===================== gather-based segment sums (fp16 features) ============

// g = 1<<LOGG lanes per node, each lane covers 2 features (half2). D = 2*g.
template<int LOGG>
__global__ __launch_bounds__(256) void k_gather_h(
    const __half2* __restrict__ feat, const int* __restrict__ rp,
    const int* __restrict__ ssrc, float2* __restrict__ agg, int n) {
  int t = blockIdx.x * 256 + threadIdx.x;
  int node = t >> LOGG;
  int f2 = t & ((1 << LOGG) - 1);
  if (node >= n) return;
  int beg = rp[node], end = rp[node + 1];
  float ax = 0.f, ay = 0.f;
  int e = beg;
  for (; e + 3 < end; e += 4) {
    int s0 = ssrc[e];
    int s1 = ssrc[e + 1];
    int s2 = ssrc[e + 2];
    int s3 = ssrc[e + 3];
    float2 v0 = __half22float2(feat[((size_t)s0 << LOGG) + f2]);
    float2 v1 = __half22float2(feat[((size_t)s1 << LOGG) + f2]);
    float2 v2 = __half22float2(feat[((size_t)s2 << LOGG) + f2]);
    float2 v3 = __half22float2(feat[((size_t)s3 << LOGG) + f2]);
    ax += v0.x; ay += v0.y;
    ax += v1.x; ay += v1.y;
    ax += v2.x; ay += v2.y;
    ax += v3.x; ay += v3.y;
  }
  for (; e < end; ++e) {
    float2 v = __half22float2(feat[((size_t)ssrc[e] << LOGG) + f2]);
    ax += v.x; ay += v.y;
  }
  agg[((size_t)node << LOGG) + f2] = make_float2(ax, ay);
}

// ===================== dense layers =====================

union U16 { uint4 u; __half2 h[4]; };

// h1 = relu(agg@w1_rel + b1 + x@w1_root), emitted as fp16
__global__ __launch_bounds__(256) void layer1_kernel(
    const float* __restrict__ x, const float* __restrict__ agg,
    const float* __restrict__ w_rel, const float* __restrict__ b,
    const float* __restrict__ w_root, __half2* __restrict__ h1h, int n) {
  __shared__ float swr[DH * DIN];   // [j][k], written linearly
  __shared__ float swo[DH * DIN];
  __shared__ float sb[DH];
  for (int idx = threadIdx.x; idx < DIN * DH; idx += blockDim.x) {
    int j = idx / DIN, k = idx % DIN;
    swr[idx] = w_rel[k * DH + j];
    swo[idx] = w_root[k * DH + j];
  }
  if (threadIdx.x < DH) sb[threadIdx.x] = b[threadIdx.x];
  __syncthreads();
  int i = blockIdx.x * blockDim.x + threadIdx.x;
  if (i >= n) return;
  float xr[DIN], ar[DIN];
  const float4* xp = (const float4*)(x + (size_t)i * DIN);
  const float4* ap = (const float4*)(agg + (size_t)i * DIN);
#pragma unroll
  for (int q = 0; q < DIN / 4; ++q) {
    float4 v = xp[q];
    xr[q*4+0] = v.x; xr[q*4+1] = v.y; xr[q*4+2] = v.z; xr[q*4+3] = v.w;
    float4 a = ap[q];
    ar[q*4+0] = a.x; ar[q*4+1] = a.y; ar[q*4+2] = a.z; ar[q*4+3] = a.w;
  }
  for (int j = 0; j < DH; j += 2) {
    float acc0 = sb[j], acc1 = sb[j + 1];
#pragma unroll
    for (int k = 0; k < DIN; ++k) {
      acc0 = fmaf(ar[k], swr[j*DIN+k],     fmaf(xr[k], swo[j*DIN+k],     acc0));
      acc1 = fmaf(ar[k], swr[(j+1)*DIN+k], fmaf(xr[k], swo[(j+1)*DIN+k], acc1));
    }
    h1h[(size_t)i * (DH/2) + (j >> 1)] =
        __floats2half2_rn(fmaxf(acc0, 0.f), fmaxf(acc1, 0.f));
  }
}

// h2 = relu(agg@w2_rel + b2 + h1@w2_root); s = h2@w3_rel  (h1 is fp16)
__global__ __launch_bounds__(256) void layer2_kernel(
    const __half2* __restrict__ h1h, const float* __restrict__ agg,
    const float* __restrict__ w_rel, const float* __restrict__ b,
    const float* __restrict__ w_root, const float* __restrict__ w3_rel,
    float* __restrict__ h2, float* __restrict__ s_out, int n) {
  __shared__ float swr[DH * DH];    // [j][k], linear writes
  __shared__ float swo[DH * DH];
  __shared__ float sb[DH];
  __shared__ float sw3[DH];
  for (int idx = threadIdx.x; idx < DH * DH; idx += blockDim.x) {
    int j = idx / DH, k = idx % DH;
    swr[idx] = w_rel[k * DH + j];
    swo[idx] = w_root[k * DH + j];
  }
  if (threadIdx.x < DH) {
    sb[threadIdx.x]  = b[threadIdx.x];
    sw3[threadIdx.x] = w3_rel[threadIdx.x];
  }
  __syncthreads();
  int i = blockIdx.x * blockDim.x + threadIdx.x;
  if (i >= n) return;
  float hr[DH], ar[DH];
  const uint4* hp = (const uint4*)(h1h + (size_t)i * (DH/2));
#pragma unroll
  for (int q = 0; q < DH / 8; ++q) {
    U16 u; u.u = hp[q];
#pragma unroll
    for (int c = 0; c < 4; ++c) {
      float2 v = __half22float2(u.h[c]);
      hr[q*8 + 2*c]     = v.x;
      hr[q*8 + 2*c + 1] = v.y;
    }
  }
  const float4* ap = (const float4*)(agg + (size_t)i * DH);
#pragma unroll
  for (int q = 0; q < DH / 4; ++q) {
    float4 a = ap[q];
    ar[q*4+0] = a.x; ar[q*4+1] = a.y; ar[q*4+2] = a.z; ar[q*4+3] = a.w;
  }
  float sdot = 0.f;
  for (int j = 0; j < DH; ++j) {
    float acc = sb[j];
#pragma unroll
    for (int k = 0; k < DH; ++k)
      acc = fmaf(ar[k], swr[j*DH+k], fmaf(hr[k], swo[j*DH+k], acc));
    float r = fmaxf(acc, 0.f);
    h2[(size_t)i * DH + j] = r;
    sdot = fmaf(r, sw3[j], sdot);
  }
  s_out[i] = sdot;
}

// fused: out = segsum(sv) + b3 + h2@w3_root
__global__ __launch_bounds__(256) void k_final(
    const float* __restrict__ sv, const int* __restrict__ rp,
    const int* __restrict__ ssrc, const float* __restrict__ h2,
    const float* __restrict__ w3_root, const float* __restrict__ b3,
    float* __restrict__ out, int n) {
  __shared__ float sw[DH];
  if (threadIdx.x < DH) sw[threadIdx.x] = w3_root[threadIdx.x];
  __syncthreads();
  int i = blockIdx.x * 256 + threadIdx.x;
  if (i >= n) return;
  int beg = rp[i], end = rp[i + 1];
  float a = b3[0];
  int e = beg;
  for (; e + 3 < end; e += 4) {
    float v0 = sv[ssrc[e]];
    float v1 = sv[ssrc[e + 1]];
    float v2 = sv[ssrc[e + 2]];
    float v3 = sv[ssrc[e + 3]];
    a += v0; a += v1; a += v2; a += v3;
  }
  for (; e < end; ++e) a += sv[ssrc[e]];
  const float4* hp = (const float4*)(h2 + (size_t)i * DH);
#pragma unroll
  for (int q = 0; q < DH / 4; ++q) {
    float4 v = hp[q];
    a = fmaf(v.x, sw[q*4+0], a);
    a = fmaf(v.y, sw[q*4+1], a);
    a = fmaf(v.z, sw[q*4+2], a);
    a = fmaf(v.w, sw[q*4+3], a);
  }
  out[i] = a;
}

// ===================== launch =====================

extern "C" void kernel_launch(void* const* d_in, const int* in_sizes, int n_in,
                              void* d_out, int out_size, void* d_ws, size_t ws_size,
                              hipStream_t stream) {
  const float* x       = (const float*)d_in[0];
  const float* w1_rel  = (const float*)d_in[1];
  const float* b1      = (const float*)d_in[2];
  const float* w1_root = (const float*)d_in[3];
  const float* w2_rel  = (const float*)d_in[4];
  const float* b2      = (const float*)d_in[5];
  const float* w2_root = (const float*)d_in[6];
  const float* w3_rel  = (const float*)d_in[7];
  const float* b3      = (const float*)d_in[8];
  const float* w3_root = (const float*)d_in[9];
  const int*   edge    = (const int*)d_in[10];

  const int n = in_sizes[0] / DIN;        // 100000 (< 2^17 required by packing)
  const int E = in_sizes[10] / 2;         // 1600000
  const int* src = edge;
  const int* dst = edge + E;

  const size_t n64 = (size_t)n * DH;
  float*   AGG  = (float*)d_ws;                 // n*64 f32 (layer1 uses n*32)
  float*   H2   = AGG + n64;                    // n*64 f32
  __half2* H1h  = (__half2*)(H2 + n64);         // n*32 half2
  __half2* XH   = H1h + (size_t)n * (DH/2);     // n*16 half2
  float*   S    = (float*)(XH + (size_t)n * (DIN/2)); // n
  float*   SACC = S + n;                        // n (unused now, kept for layout)
  int* RP   = (int*)(SACC + n);                 // n+1
  int* CUR  = RP + (n + 1);                     // n (degree buffer)
  int* SSRC = CUR + n;                          // E
  int* BSUM = SSRC + E;                         // <=256
  int* BCUR = BSUM + 256;                       // <=512 coarse-bucket cursors
  unsigned* BIN = (unsigned*)H2;                // E (dead before layer2 writes H2)

  const int B = 256;
  const int gn = (n + B - 1) / B;
  const int gE = (E + B - 1) / B;
  const int nb = (n + 1023) / 1024;
  const int nbuckets = (n + 255) >> NBSHIFT;    // 391
  const int gA = (E + TILE_A - 1) / TILE_A;     // 98

  // ---- CSR build (two-level counting sort by dst) ----
  hipMemsetAsync(CUR, 0, (size_t)n * sizeof(int), stream);
  k_hist<<<gE, B, 0, stream>>>(dst, CUR, E);
  k_scan1<<<nb, B, 0, stream>>>(CUR, RP, BSUM, n);
  k_scan2<<<1, B, 0, stream>>>(BSUM, nb);
  k_scan3<<<(n + 1 + B - 1) / B, B, 0, stream>>>(RP, BSUM, BCUR, n, E);
  k_binA<<<gA, B, 0, stream>>>(src, dst, BCUR, BIN, E, nbuckets);
  k_fillB<<<nbuckets, B, 0, stream>>>(BIN, RP, SSRC, n);

  // ---- x -> fp16 ----
  {
    int n2 = n * (DIN / 2);
    k_tohalf<<<(n2 + B - 1) / B, B, 0, stream>>>((const float2*)x, XH, n2);
  }

  // ---- layer 1 ----  (16 lanes/node, 32 features)
  {
    long long tot = (long long)n * (DIN / 2);
    k_gather_h<4><<<(unsigned)((tot + B - 1) / B), B, 0, stream>>>(
        XH, RP, SSRC, (float2*)AGG, n);
  }
  layer1_kernel<<<gn, B, 0, stream>>>(x, AGG, w1_rel, b1, w1_root, H1h, n);

  // ---- layer 2 ----  (32 lanes/node, 64 features)
  {
    long long tot = (long long)n * (DH / 2);
    k_gather_h<5><<<(unsigned)((tot + B - 1) / B), B, 0, stream>>>(
        H1h, RP, SSRC, (float2*)AGG, n);
  }
  layer2_kernel<<<gn, B, 0, stream>>>(H1h, AGG, w2_rel, b2, w2_root, w3_rel, H2, S, n);

  // ---- layer 3 (pre-projected by w3_rel in layer2_kernel) ----
  k_final<<<gn, B, 0, stream>>>(S, RP, SSRC, H2, w3_root, b3, (float*)d_out, n);
}